// Round 1
// baseline (381.239 us; speedup 1.0000x reference)
//
#include <hip/hip_runtime.h>
#include <stdint.h>
#include <stddef.h>

typedef unsigned short u16;
typedef __attribute__((ext_vector_type(8))) short bf16x8;
typedef __attribute__((ext_vector_type(4))) float f32x4;
typedef __attribute__((ext_vector_type(4))) unsigned short u16x4;

#define MFMA_BF16 __builtin_amdgcn_mfma_f32_16x16x32_bf16
#define VMCNT0 asm volatile("s_waitcnt vmcnt(0)" ::: "memory")

// round-to-nearest-even fp32 -> bf16 (values are well-behaved; no NaN/Inf path needed)
__device__ __forceinline__ u16 f2b(float x) {
  uint32_t u = __builtin_bit_cast(uint32_t, x);
  return (u16)((u + 0x7fffu + ((u >> 16) & 1u)) >> 16);
}

// async global->LDS, 16B per lane. LDS dst must be wave-uniform base; HW adds lane*16.
__device__ __forceinline__ void async16(const void* g, void* l) {
  __builtin_amdgcn_global_load_lds((const __attribute__((address_space(1))) void*)g,
                                   (__attribute__((address_space(3))) void*)l, 16, 0, 0);
}

// ---------------------------------------------------------------- converts
__global__ void cvt_bf16(const float* __restrict__ src, u16* __restrict__ dst, int n) {
  int i = (blockIdx.x * 256 + threadIdx.x) * 4;
  if (i < n) {
    float4 v = *(const float4*)(src + i);
    u16x4 o = { f2b(v.x), f2b(v.y), f2b(v.z), f2b(v.w) };
    *(u16x4*)(dst + i) = o;
  }
}

// ---------------------------------------------------------------- QKV GEMM
// C[m,j] = sum_k A[m,k]*W[j,k];  M=8192, Ncols=2304, K=768.
// Epilogue scatters: j in [0,768) -> Q (x0.125), [768,1536) -> K, [1536,2304) -> V^T.
// Q/K layout: [b,h,n,d]; V stored transposed: [b,h,d,n].
__global__ __launch_bounds__(256, 2)
void qkv_gemm(const u16* __restrict__ Xb, const u16* __restrict__ Yb,
              const u16* __restrict__ Wx, const u16* __restrict__ Wy,
              u16* __restrict__ Qx, u16* __restrict__ Kx, u16* __restrict__ Vtx,
              u16* __restrict__ Qy, u16* __restrict__ Ky, u16* __restrict__ Vty) {
  __shared__ alignas(16) u16 As[128 * 64];
  __shared__ alignas(16) u16 Bs[128 * 64];
  const int br = blockIdx.z;
  const u16* A = br ? Yb : Xb;
  const u16* W = br ? Wy : Wx;
  u16* Qd = br ? Qy : Qx;
  u16* Kd = br ? Ky : Kx;
  u16* Vd = br ? Vty : Vtx;
  const int m0 = blockIdx.x * 128;
  const int j0 = blockIdx.y * 128;
  const int tid = threadIdx.x;
  const int wave = tid >> 6, lane = tid & 63;
  const int quad = lane >> 4, l16 = lane & 15;
  const int wm = wave >> 1, wn = wave & 1;
  const int srow = wave * 32 + (lane >> 3);  // +c*8
  const int scol = (lane & 7) * 8;

  f32x4 acc[4][4] = {};

  for (int k0 = 0; k0 < 768; k0 += 64) {
#pragma unroll
    for (int c = 0; c < 4; ++c) {
      async16(A + (size_t)(m0 + srow + c * 8) * 768 + k0 + scol,
              (char*)As + wave * 4096 + c * 1024);
      async16(W + (size_t)(j0 + srow + c * 8) * 768 + k0 + scol,
              (char*)Bs + wave * 4096 + c * 1024);
    }
    VMCNT0;
    __syncthreads();
#pragma unroll
    for (int kc = 0; kc < 2; ++kc) {
      bf16x8 af[4], bfr[4];
#pragma unroll
      for (int t = 0; t < 4; ++t) {
        af[t]  = *(const bf16x8*)&As[(wm * 64 + t * 16 + l16) * 64 + kc * 32 + quad * 8];
        bfr[t] = *(const bf16x8*)&Bs[(wn * 64 + t * 16 + l16) * 64 + kc * 32 + quad * 8];
      }
#pragma unroll
      for (int mt = 0; mt < 4; ++mt)
#pragma unroll
        for (int nt = 0; nt < 4; ++nt)
          acc[mt][nt] = MFMA_BF16(af[mt], bfr[nt], acc[mt][nt], 0, 0, 0);
    }
    __syncthreads();
  }

  const int s3 = j0 / 768;  // 0=Q 1=K 2=V, uniform per block (768/128=6 blocks each)
#pragma unroll
  for (int mt = 0; mt < 4; ++mt) {
#pragma unroll
    for (int nt = 0; nt < 4; ++nt) {
      const int j = j0 + wn * 64 + nt * 16 + l16;
      const int jr = j - s3 * 768;
      const int h = jr >> 6, d = jr & 63;
#pragma unroll
      for (int r = 0; r < 4; ++r) {
        const int m = m0 + wm * 64 + mt * 16 + quad * 4 + r;
        const int b = m >> 10, n = m & 1023;
        const size_t bh = (size_t)(b * 12 + h);
        const float v = acc[mt][nt][r];
        if (s3 == 0)      Qd[(bh * 1024 + n) * 64 + d] = f2b(v * 0.125f);
        else if (s3 == 1) Kd[(bh * 1024 + n) * 64 + d] = f2b(v);
        else              Vd[(bh * 64 + d) * 1024 + n] = f2b(v);
      }
    }
  }
}

// ---------------------------------------------------------------- flash attention
// Per block: one (branch, b*h, 128-row q tile). No max-tracking (scores are small):
// O += exp(S) @ V, l += rowsum(exp(S)), final O/l. Q is pre-scaled by 0.125.
__global__ __launch_bounds__(256, 2)
void attn_kernel(const u16* __restrict__ Qx, const u16* __restrict__ Kx, const u16* __restrict__ Vtx,
                 const u16* __restrict__ Qy, const u16* __restrict__ Ky, const u16* __restrict__ Vty,
                 u16* __restrict__ Ox, u16* __restrict__ Oy) {
  __shared__ alignas(16) u16 Ks[64 * 64];    // [kv][d]
  __shared__ alignas(16) u16 Vs[64 * 64];    // [d][kv]  (V^T tile)
  __shared__ alignas(16) u16 Ps[128 * 72];   // [q][kv], padded +8 -> conflict-free b128
  const int br = blockIdx.z;
  const u16* Q = br ? Qy : Qx;
  const u16* K = br ? Ky : Kx;
  const u16* V = br ? Vtx : Vty;  // swapped-V cross attention
  u16* O = br ? Oy : Ox;
  const int bh = blockIdx.y;
  const int q0 = blockIdx.x * 128;
  const int tid = threadIdx.x;
  const int wave = tid >> 6, lane = tid & 63;
  const int quad = lane >> 4, l16 = lane & 15;

  const u16* Qb = Q + (size_t)bh * 65536;
  const u16* Kb = K + (size_t)bh * 65536;
  const u16* Vb = V + (size_t)bh * 65536;

  // loop-invariant Q A-fragments straight from global
  bf16x8 qf[2][2];
#pragma unroll
  for (int mt = 0; mt < 2; ++mt)
#pragma unroll
    for (int kc = 0; kc < 2; ++kc)
      qf[mt][kc] = *(const bf16x8*)(Qb + (size_t)(q0 + wave * 32 + mt * 16 + l16) * 64 + kc * 32 + quad * 8);

  f32x4 oacc[2][4] = {};
  float lacc[2][4] = {};

  for (int kv0 = 0; kv0 < 1024; kv0 += 64) {
    // stage K tile (contiguous 8KB) and V^T tile (64 rows x 128B)
#pragma unroll
    for (int c = 0; c < 2; ++c) {
      async16((const char*)(Kb + (size_t)kv0 * 64) + wave * 2048 + c * 1024 + lane * 16,
              (char*)Ks + wave * 2048 + c * 1024);
      const int vrow = wave * 16 + c * 8 + (lane >> 3);
      async16(Vb + (size_t)vrow * 1024 + kv0 + (lane & 7) * 8,
              (char*)Vs + wave * 2048 + c * 1024);
    }
    VMCNT0;
    __syncthreads();

    // S = Q K^T  (wave owns 32 q rows x 64 kv cols)
    f32x4 sc[2][4] = {};
#pragma unroll
    for (int kc = 0; kc < 2; ++kc) {
      bf16x8 kf[4];
#pragma unroll
      for (int nt = 0; nt < 4; ++nt)
        kf[nt] = *(const bf16x8*)&Ks[(nt * 16 + l16) * 64 + kc * 32 + quad * 8];
#pragma unroll
      for (int mt = 0; mt < 2; ++mt)
#pragma unroll
        for (int nt = 0; nt < 4; ++nt)
          sc[mt][nt] = MFMA_BF16(qf[mt][kc], kf[nt], sc[mt][nt], 0, 0, 0);
    }

    // P = exp(S): write bf16 P to LDS (C-layout -> A-layout transpose) + row sums
#pragma unroll
    for (int mt = 0; mt < 2; ++mt) {
      float tt[4] = {0.f, 0.f, 0.f, 0.f};
      const int prow = wave * 32 + mt * 16 + quad * 4;
#pragma unroll
      for (int nt = 0; nt < 4; ++nt) {
        const int pcol = nt * 16 + l16;
#pragma unroll
        for (int r = 0; r < 4; ++r) {
          const float pv = __expf(sc[mt][nt][r]);
          tt[r] += pv;
          Ps[(prow + r) * 72 + pcol] = f2b(pv);
        }
      }
#pragma unroll
      for (int r = 0; r < 4; ++r) {
        float v = tt[r];
        v += __shfl_xor(v, 1, 64);
        v += __shfl_xor(v, 2, 64);
        v += __shfl_xor(v, 4, 64);
        v += __shfl_xor(v, 8, 64);
        lacc[mt][r] += v;  // row-sum over this 64-kv tile, replicated across 16 lanes
      }
    }
    __syncthreads();

    // O += P @ V   (A = P from LDS, B = V^T tile)
#pragma unroll
    for (int kc = 0; kc < 2; ++kc) {
      bf16x8 pf[2], vf[4];
#pragma unroll
      for (int mt = 0; mt < 2; ++mt)
        pf[mt] = *(const bf16x8*)&Ps[(wave * 32 + mt * 16 + l16) * 72 + kc * 32 + quad * 8];
#pragma unroll
      for (int nt = 0; nt < 4; ++nt)
        vf[nt] = *(const bf16x8*)&Vs[(nt * 16 + l16) * 64 + kc * 32 + quad * 8];
#pragma unroll
      for (int mt = 0; mt < 2; ++mt)
#pragma unroll
        for (int nt = 0; nt < 4; ++nt)
          oacc[mt][nt] = MFMA_BF16(pf[mt], vf[nt], oacc[mt][nt], 0, 0, 0);
    }
    __syncthreads();
  }

  // epilogue: O / l -> bf16 [b, n, h*64+d] (k-contiguous for proj GEMM)
  const int b = bh / 12, h = bh % 12;
#pragma unroll
  for (int mt = 0; mt < 2; ++mt) {
#pragma unroll
    for (int r = 0; r < 4; ++r) {
      const float inv = 1.0f / lacc[mt][r];
      const int qrow = q0 + wave * 32 + mt * 16 + quad * 4 + r;
      const size_t ob = ((size_t)(b * 1024 + qrow)) * 768 + h * 64;
#pragma unroll
      for (int nt = 0; nt < 4; ++nt)
        O[ob + nt * 16 + l16] = f2b(oacc[mt][nt][r] * inv);
    }
  }
}

// ---------------------------------------------------------------- proj GEMM + bias
__global__ __launch_bounds__(256, 2)
void proj_gemm(const u16* __restrict__ Ox, const u16* __restrict__ Oy,
               const u16* __restrict__ Pxw, const u16* __restrict__ Pyw,
               const float* __restrict__ bx, const float* __restrict__ by,
               float* __restrict__ out) {
  __shared__ alignas(16) u16 As[128 * 64];
  __shared__ alignas(16) u16 Bs[128 * 64];
  const int br = blockIdx.z;
  const u16* A = br ? Oy : Ox;
  const u16* W = br ? Pyw : Pxw;
  const float* bias = br ? by : bx;
  float* op = out + (size_t)br * 6291456;
  const int m0 = blockIdx.x * 128;
  const int j0 = blockIdx.y * 128;
  const int tid = threadIdx.x;
  const int wave = tid >> 6, lane = tid & 63;
  const int quad = lane >> 4, l16 = lane & 15;
  const int wm = wave >> 1, wn = wave & 1;
  const int srow = wave * 32 + (lane >> 3);
  const int scol = (lane & 7) * 8;

  f32x4 acc[4][4] = {};

  for (int k0 = 0; k0 < 768; k0 += 64) {
#pragma unroll
    for (int c = 0; c < 4; ++c) {
      async16(A + (size_t)(m0 + srow + c * 8) * 768 + k0 + scol,
              (char*)As + wave * 4096 + c * 1024);
      async16(W + (size_t)(j0 + srow + c * 8) * 768 + k0 + scol,
              (char*)Bs + wave * 4096 + c * 1024);
    }
    VMCNT0;
    __syncthreads();
#pragma unroll
    for (int kc = 0; kc < 2; ++kc) {
      bf16x8 af[4], bfr[4];
#pragma unroll
      for (int t = 0; t < 4; ++t) {
        af[t]  = *(const bf16x8*)&As[(wm * 64 + t * 16 + l16) * 64 + kc * 32 + quad * 8];
        bfr[t] = *(const bf16x8*)&Bs[(wn * 64 + t * 16 + l16) * 64 + kc * 32 + quad * 8];
      }
#pragma unroll
      for (int mt = 0; mt < 4; ++mt)
#pragma unroll
        for (int nt = 0; nt < 4; ++nt)
          acc[mt][nt] = MFMA_BF16(af[mt], bfr[nt], acc[mt][nt], 0, 0, 0);
    }
    __syncthreads();
  }

#pragma unroll
  for (int mt = 0; mt < 4; ++mt) {
#pragma unroll
    for (int nt = 0; nt < 4; ++nt) {
      const int j = j0 + wn * 64 + nt * 16 + l16;
      const float bj = bias[j];
#pragma unroll
      for (int r = 0; r < 4; ++r) {
        const int m = m0 + wm * 64 + mt * 16 + quad * 4 + r;
        op[(size_t)m * 768 + j] = acc[mt][nt][r] + bj;
      }
    }
  }
}

// ---------------------------------------------------------------- launch
extern "C" void kernel_launch(void* const* d_in, const int* in_sizes, int n_in,
                              void* d_out, int out_size, void* d_ws, size_t ws_size,
                              hipStream_t stream) {
  (void)in_sizes; (void)n_in; (void)out_size; (void)ws_size;
  const float* x   = (const float*)d_in[0];
  const float* y   = (const float*)d_in[1];
  const float* xqw = (const float*)d_in[2];
  const float* yqw = (const float*)d_in[3];
  const float* xpw = (const float*)d_in[4];
  const float* xpb = (const float*)d_in[5];
  const float* ypw = (const float*)d_in[6];
  const float* ypb = (const float*)d_in[7];
  float* out = (float*)d_out;

  char* p = (char*)d_ws;
  u16* Xb  = (u16*)p; p += 12582912;   // 8192x768 bf16
  u16* Yb  = (u16*)p; p += 12582912;
  u16* Wxb = (u16*)p; p += 3538944;    // 2304x768 bf16
  u16* Wyb = (u16*)p; p += 3538944;
  u16* Pxb = (u16*)p; p += 1179648;    // 768x768 bf16
  u16* Pyb = (u16*)p; p += 1179648;
  u16* Qx  = (u16*)p; p += 12582912;   // [b,h,n,d] bf16 (pre-scaled)
  u16* Kx  = (u16*)p; p += 12582912;
  u16* Vtx = (u16*)p; p += 12582912;   // [b,h,d,n] bf16
  u16* Qy  = (u16*)p; p += 12582912;
  u16* Ky  = (u16*)p; p += 12582912;
  u16* Vty = (u16*)p; p += 12582912;
  u16* Ox  = Xb;  // alias: Xb/Yb dead after qkv_gemm (stream-ordered)
  u16* Oy  = Yb;

  cvt_bf16<<<6144, 256, 0, stream>>>(x,   Xb,  6291456);
  cvt_bf16<<<6144, 256, 0, stream>>>(y,   Yb,  6291456);
  cvt_bf16<<<1728, 256, 0, stream>>>(xqw, Wxb, 1769472);
  cvt_bf16<<<1728, 256, 0, stream>>>(yqw, Wyb, 1769472);
  cvt_bf16<<<576,  256, 0, stream>>>(xpw, Pxb, 589824);
  cvt_bf16<<<576,  256, 0, stream>>>(ypw, Pyb, 589824);

  qkv_gemm<<<dim3(64, 18, 2), 256, 0, stream>>>(Xb, Yb, Wxb, Wyb,
                                                Qx, Kx, Vtx, Qy, Ky, Vty);
  attn_kernel<<<dim3(8, 96, 2), 256, 0, stream>>>(Qx, Kx, Vtx, Qy, Ky, Vty, Ox, Oy);
  proj_gemm<<<dim3(64, 6, 2), 256, 0, stream>>>(Ox, Oy, Pxb, Pyb, xpb, ypb, out);
}

// Round 2
// 315.636 us; speedup vs baseline: 1.2078x; 1.2078x over previous
//
#include <hip/hip_runtime.h>
#include <stdint.h>
#include <stddef.h>

typedef unsigned short u16;
typedef __attribute__((ext_vector_type(8))) short bf16x8;
typedef __attribute__((ext_vector_type(4))) float f32x4;
typedef __attribute__((ext_vector_type(4))) unsigned short u16x4;

#define MFMA_BF16 __builtin_amdgcn_mfma_f32_16x16x32_bf16
#define VMCNT0 asm volatile("s_waitcnt vmcnt(0)" ::: "memory")
// raw barrier: wait own vmcnt (tile landed) then barrier. Prefetch for the NEXT
// tile is issued AFTER this, so the wait only covers loads that flew during the
// previous compute phase.
#define BAR_FULL asm volatile("s_waitcnt vmcnt(0)\n\ts_barrier" ::: "memory")

// round-to-nearest-even fp32 -> bf16
__device__ __forceinline__ u16 f2b(float x) {
  uint32_t u = __builtin_bit_cast(uint32_t, x);
  return (u16)((u + 0x7fffu + ((u >> 16) & 1u)) >> 16);
}

// async global->LDS, 16B per lane. LDS dst is wave-uniform base + lane*16.
__device__ __forceinline__ void async16(const void* g, void* l) {
  __builtin_amdgcn_global_load_lds((const __attribute__((address_space(1))) void*)g,
                                   (__attribute__((address_space(3))) void*)l, 16, 0, 0);
}

// ---------------------------------------------------------------- fused converts
// All six bf16 destinations are contiguous in d_ws in this order:
// Xb(6291456) Yb(6291456) Wxb(1769472) Wyb(1769472) Pxb(589824) Pyb(589824)
__global__ void cvt_all(const float* __restrict__ x, const float* __restrict__ y,
                        const float* __restrict__ xqw, const float* __restrict__ yqw,
                        const float* __restrict__ xpw, const float* __restrict__ ypw,
                        u16* __restrict__ dst) {
  long i = ((long)blockIdx.x * 256 + threadIdx.x) * 4;
  const float* src;
  long off;
  if (i < 6291456)       { src = x;   off = 0; }
  else if (i < 12582912) { src = y;   off = 6291456; }
  else if (i < 14352384) { src = xqw; off = 12582912; }
  else if (i < 16121856) { src = yqw; off = 14352384; }
  else if (i < 16711680) { src = xpw; off = 16121856; }
  else                   { src = ypw; off = 16711680; }
  float4 v = *(const float4*)(src + (i - off));
  u16x4 o = { f2b(v.x), f2b(v.y), f2b(v.z), f2b(v.w) };
  *(u16x4*)(dst + i) = o;
}

// ---------------------------------------------------------------- QKV GEMM
// C[m,j] = sum_k A[m,k]*W[j,k];  M=8192, Ncols=2304, K=768.
// LDS tiles use XOR chunk swizzle (chunk ^= row&7, applied on the global read
// side of global_load_lds) -> conflict-free ds_read_b128 fragment reads.
__global__ __launch_bounds__(256, 2)
void qkv_gemm(const u16* __restrict__ Xb, const u16* __restrict__ Yb,
              const u16* __restrict__ Wx, const u16* __restrict__ Wy,
              u16* __restrict__ Qx, u16* __restrict__ Kx, u16* __restrict__ Vtx,
              u16* __restrict__ Qy, u16* __restrict__ Ky, u16* __restrict__ Vty) {
  __shared__ alignas(16) u16 As[128 * 64];
  __shared__ alignas(16) u16 Bs[128 * 64];
  const int br = blockIdx.z;
  const u16* A = br ? Yb : Xb;
  const u16* W = br ? Wy : Wx;
  u16* Qd = br ? Qy : Qx;
  u16* Kd = br ? Ky : Kx;
  u16* Vd = br ? Vty : Vtx;
  const int m0 = blockIdx.x * 128;
  const int j0 = blockIdx.y * 128;
  const int tid = threadIdx.x;
  const int wave = tid >> 6, lane = tid & 63;
  const int quad = lane >> 4, l16 = lane & 15;
  const int wm = wave >> 1, wn = wave & 1;
  const int srow = wave * 32 + (lane >> 3);               // +c*8
  const int scol = (((lane & 7) ^ ((lane >> 3) & 7)) * 8);  // swizzled chunk
  const int l7 = l16 & 7;

  f32x4 acc[4][4] = {};

  for (int k0 = 0; k0 < 768; k0 += 64) {
#pragma unroll
    for (int c = 0; c < 4; ++c) {
      async16(A + (size_t)(m0 + srow + c * 8) * 768 + k0 + scol,
              (char*)As + wave * 4096 + c * 1024);
      async16(W + (size_t)(j0 + srow + c * 8) * 768 + k0 + scol,
              (char*)Bs + wave * 4096 + c * 1024);
    }
    VMCNT0;
    __syncthreads();
#pragma unroll
    for (int kc = 0; kc < 2; ++kc) {
      bf16x8 af[4], bfr[4];
#pragma unroll
      for (int t = 0; t < 4; ++t) {
        af[t]  = *(const bf16x8*)&As[(wm * 64 + t * 16 + l16) * 64 + (((kc * 4 + quad) ^ l7) * 8)];
        bfr[t] = *(const bf16x8*)&Bs[(wn * 64 + t * 16 + l16) * 64 + (((kc * 4 + quad) ^ l7) * 8)];
      }
#pragma unroll
      for (int mt = 0; mt < 4; ++mt)
#pragma unroll
        for (int nt = 0; nt < 4; ++nt)
          acc[mt][nt] = MFMA_BF16(af[mt], bfr[nt], acc[mt][nt], 0, 0, 0);
    }
    __syncthreads();
  }

  const int s3 = j0 / 768;  // 0=Q 1=K 2=V, uniform per block
#pragma unroll
  for (int mt = 0; mt < 4; ++mt) {
#pragma unroll
    for (int nt = 0; nt < 4; ++nt) {
      const int j = j0 + wn * 64 + nt * 16 + l16;
      const int jr = j - s3 * 768;
      const int h = jr >> 6, d = jr & 63;
#pragma unroll
      for (int r = 0; r < 4; ++r) {
        const int m = m0 + wm * 64 + mt * 16 + quad * 4 + r;
        const int b = m >> 10, n = m & 1023;
        const size_t bh = (size_t)(b * 12 + h);
        const float v = acc[mt][nt][r];
        if (s3 == 0)      Qd[(bh * 1024 + n) * 64 + d] = f2b(v * 0.125f);
        else if (s3 == 1) Kd[(bh * 1024 + n) * 64 + d] = f2b(v);
        else              Vd[(bh * 64 + d) * 1024 + n] = f2b(v);
      }
    }
  }
}

// ---------------------------------------------------------------- flash attention
// Per block: one (branch, b*h, 128-row q tile). kv tile 64, K/V double-buffered
// with prefetch across a single raw barrier per iteration. Row-sums come from an
// extra ones-B MFMA in the PV phase (matrix pipe, not LDS pipe). Ps rows are
// wave-private -> no barrier needed between exp phase and PV phase.
__global__ __launch_bounds__(256, 3)
void attn_kernel(const u16* __restrict__ Qx, const u16* __restrict__ Kx, const u16* __restrict__ Vtx,
                 const u16* __restrict__ Qy, const u16* __restrict__ Ky, const u16* __restrict__ Vty,
                 u16* __restrict__ Ox, u16* __restrict__ Oy) {
  __shared__ alignas(16) u16 Ks[2][64 * 64];   // [kv][d], swizzled
  __shared__ alignas(16) u16 Vs[2][64 * 64];   // [d][kv], swizzled
  __shared__ alignas(16) u16 Ps[128 * 72];     // [q][kv], padded +8
  const int br = blockIdx.z;
  const u16* Q = br ? Qy : Qx;
  const u16* K = br ? Ky : Kx;
  const u16* V = br ? Vtx : Vty;  // swapped-V cross attention
  u16* O = br ? Oy : Ox;
  const int bh = blockIdx.y;
  const int q0 = blockIdx.x * 128;
  const int tid = threadIdx.x;
  const int wave = tid >> 6, lane = tid & 63;
  const int quad = lane >> 4, l16 = lane & 15;
  const int l7 = l16 & 7;
  const int r8 = (lane >> 3) & 7;
  const int sw = ((lane & 7) ^ r8) * 8;        // swizzled chunk (u16 offset)

  const u16* Qb = Q + (size_t)bh * 65536;
  const u16* Kb = K + (size_t)bh * 65536;
  const u16* Vb = V + (size_t)bh * 65536;

  // loop-invariant Q A-fragments straight from global (Q pre-scaled by 0.125)
  bf16x8 qf[2][2];
#pragma unroll
  for (int mt = 0; mt < 2; ++mt)
#pragma unroll
    for (int kc = 0; kc < 2; ++kc)
      qf[mt][kc] = *(const bf16x8*)(Qb + (size_t)(q0 + wave * 32 + mt * 16 + l16) * 64 + kc * 32 + quad * 8);

  f32x4 oacc[2][4] = {};
  f32x4 lsum[2] = {};
  bf16x8 ones;
#pragma unroll
  for (int j = 0; j < 8; ++j) ones[j] = (short)0x3f80;  // 1.0bf16

  const int krow = wave * 16 + r8;  // +c*8; (krow+c*8)&7 == r8 -> swizzle consistent

  // prologue: stage tile 0 into buf 0
#pragma unroll
  for (int c = 0; c < 2; ++c) {
    async16(Kb + (size_t)(krow + c * 8) * 64 + sw, (char*)Ks[0] + wave * 2048 + c * 1024);
    async16(Vb + (size_t)(krow + c * 8) * 1024 + sw, (char*)Vs[0] + wave * 2048 + c * 1024);
  }

  for (int it = 0; it < 16; ++it) {
    const int p = it & 1;
    BAR_FULL;  // tile `it` landed everywhere; prior reads of buf p^1 are sealed
    if (it < 15) {
      const int kv1 = (it + 1) * 64;
#pragma unroll
      for (int c = 0; c < 2; ++c) {
        async16(Kb + (size_t)(kv1 + krow + c * 8) * 64 + sw, (char*)Ks[p ^ 1] + wave * 2048 + c * 1024);
        async16(Vb + (size_t)(krow + c * 8) * 1024 + kv1 + sw, (char*)Vs[p ^ 1] + wave * 2048 + c * 1024);
      }
    }

    // S = Q K^T  (wave owns 32 q rows x 64 kv cols)
    f32x4 sc[2][4] = {};
#pragma unroll
    for (int kc = 0; kc < 2; ++kc) {
      bf16x8 kf[4];
#pragma unroll
      for (int nt = 0; nt < 4; ++nt)
        kf[nt] = *(const bf16x8*)&Ks[p][(nt * 16 + l16) * 64 + (((kc * 4 + quad) ^ l7) * 8)];
#pragma unroll
      for (int mt = 0; mt < 2; ++mt)
#pragma unroll
        for (int nt = 0; nt < 4; ++nt)
          sc[mt][nt] = MFMA_BF16(qf[mt][kc], kf[nt], sc[mt][nt], 0, 0, 0);
    }

    // P = exp(S) -> Ps (C-layout -> A-layout transpose through LDS, own rows only)
#pragma unroll
    for (int mt = 0; mt < 2; ++mt) {
      const int prow = wave * 32 + mt * 16 + quad * 4;
#pragma unroll
      for (int nt = 0; nt < 4; ++nt) {
        const int pcol = nt * 16 + l16;
#pragma unroll
        for (int r = 0; r < 4; ++r)
          Ps[(prow + r) * 72 + pcol] = f2b(__expf(sc[mt][nt][r]));
      }
    }

    // O += P @ V ; lsum += P @ ones  (row sums on the matrix pipe)
#pragma unroll
    for (int kc = 0; kc < 2; ++kc) {
      bf16x8 pf[2], vf[4];
#pragma unroll
      for (int mt = 0; mt < 2; ++mt)
        pf[mt] = *(const bf16x8*)&Ps[(wave * 32 + mt * 16 + l16) * 72 + kc * 32 + quad * 8];
#pragma unroll
      for (int nt = 0; nt < 4; ++nt)
        vf[nt] = *(const bf16x8*)&Vs[p][(nt * 16 + l16) * 64 + (((kc * 4 + quad) ^ l7) * 8)];
#pragma unroll
      for (int mt = 0; mt < 2; ++mt) {
#pragma unroll
        for (int nt = 0; nt < 4; ++nt)
          oacc[mt][nt] = MFMA_BF16(pf[mt], vf[nt], oacc[mt][nt], 0, 0, 0);
        lsum[mt] = MFMA_BF16(pf[mt], ones, lsum[mt], 0, 0, 0);
      }
    }
  }

  // epilogue: O / l -> bf16 [b, n, h*64+d]
  const int b = bh / 12, h = bh % 12;
#pragma unroll
  for (int mt = 0; mt < 2; ++mt) {
#pragma unroll
    for (int r = 0; r < 4; ++r) {
      const float inv = 1.0f / lsum[mt][r];
      const int qrow = q0 + wave * 32 + mt * 16 + quad * 4 + r;
      const size_t ob = ((size_t)(b * 1024 + qrow)) * 768 + h * 64;
#pragma unroll
      for (int nt = 0; nt < 4; ++nt)
        O[ob + nt * 16 + l16] = f2b(oacc[mt][nt][r] * inv);
    }
  }
}

// ---------------------------------------------------------------- proj GEMM + bias
__global__ __launch_bounds__(256, 2)
void proj_gemm(const u16* __restrict__ Ox, const u16* __restrict__ Oy,
               const u16* __restrict__ Pxw, const u16* __restrict__ Pyw,
               const float* __restrict__ bx, const float* __restrict__ by,
               float* __restrict__ out) {
  __shared__ alignas(16) u16 As[128 * 64];
  __shared__ alignas(16) u16 Bs[128 * 64];
  const int br = blockIdx.z;
  const u16* A = br ? Oy : Ox;
  const u16* W = br ? Pyw : Pxw;
  const float* bias = br ? by : bx;
  float* op = out + (size_t)br * 6291456;
  const int m0 = blockIdx.x * 128;
  const int j0 = blockIdx.y * 128;
  const int tid = threadIdx.x;
  const int wave = tid >> 6, lane = tid & 63;
  const int quad = lane >> 4, l16 = lane & 15;
  const int wm = wave >> 1, wn = wave & 1;
  const int srow = wave * 32 + (lane >> 3);
  const int scol = (((lane & 7) ^ ((lane >> 3) & 7)) * 8);
  const int l7 = l16 & 7;

  f32x4 acc[4][4] = {};

  for (int k0 = 0; k0 < 768; k0 += 64) {
#pragma unroll
    for (int c = 0; c < 4; ++c) {
      async16(A + (size_t)(m0 + srow + c * 8) * 768 + k0 + scol,
              (char*)As + wave * 4096 + c * 1024);
      async16(W + (size_t)(j0 + srow + c * 8) * 768 + k0 + scol,
              (char*)Bs + wave * 4096 + c * 1024);
    }
    VMCNT0;
    __syncthreads();
#pragma unroll
    for (int kc = 0; kc < 2; ++kc) {
      bf16x8 af[4], bfr[4];
#pragma unroll
      for (int t = 0; t < 4; ++t) {
        af[t]  = *(const bf16x8*)&As[(wm * 64 + t * 16 + l16) * 64 + (((kc * 4 + quad) ^ l7) * 8)];
        bfr[t] = *(const bf16x8*)&Bs[(wn * 64 + t * 16 + l16) * 64 + (((kc * 4 + quad) ^ l7) * 8)];
      }
#pragma unroll
      for (int mt = 0; mt < 4; ++mt)
#pragma unroll
        for (int nt = 0; nt < 4; ++nt)
          acc[mt][nt] = MFMA_BF16(af[mt], bfr[nt], acc[mt][nt], 0, 0, 0);
    }
    __syncthreads();
  }

#pragma unroll
  for (int mt = 0; mt < 4; ++mt) {
#pragma unroll
    for (int nt = 0; nt < 4; ++nt) {
      const int j = j0 + wn * 64 + nt * 16 + l16;
      const float bj = bias[j];
#pragma unroll
      for (int r = 0; r < 4; ++r) {
        const int m = m0 + wm * 64 + mt * 16 + quad * 4 + r;
        op[(size_t)m * 768 + j] = acc[mt][nt][r] + bj;
      }
    }
  }
}

// ---------------------------------------------------------------- launch
extern "C" void kernel_launch(void* const* d_in, const int* in_sizes, int n_in,
                              void* d_out, int out_size, void* d_ws, size_t ws_size,
                              hipStream_t stream) {
  (void)in_sizes; (void)n_in; (void)out_size; (void)ws_size;
  const float* x   = (const float*)d_in[0];
  const float* y   = (const float*)d_in[1];
  const float* xqw = (const float*)d_in[2];
  const float* yqw = (const float*)d_in[3];
  const float* xpw = (const float*)d_in[4];
  const float* xpb = (const float*)d_in[5];
  const float* ypw = (const float*)d_in[6];
  const float* ypb = (const float*)d_in[7];
  float* out = (float*)d_out;

  char* p = (char*)d_ws;
  u16* Xb  = (u16*)p; p += 12582912;   // 8192x768 bf16   } these six are
  u16* Yb  = (u16*)p; p += 12582912;   //                 } contiguous: cvt_all
  u16* Wxb = (u16*)p; p += 3538944;    // 2304x768 bf16   } writes them as one
  u16* Wyb = (u16*)p; p += 3538944;    //                 } flat array
  u16* Pxb = (u16*)p; p += 1179648;    // 768x768 bf16
  u16* Pyb = (u16*)p; p += 1179648;
  u16* Qx  = (u16*)p; p += 12582912;   // [b,h,n,d] bf16 (pre-scaled)
  u16* Kx  = (u16*)p; p += 12582912;
  u16* Vtx = (u16*)p; p += 12582912;   // [b,h,d,n] bf16
  u16* Qy  = (u16*)p; p += 12582912;
  u16* Ky  = (u16*)p; p += 12582912;
  u16* Vty = (u16*)p; p += 12582912;
  u16* Ox  = Xb;  // alias: Xb/Yb dead after qkv_gemm (stream-ordered)
  u16* Oy  = Yb;

  cvt_all<<<16896, 256, 0, stream>>>(x, y, xqw, yqw, xpw, ypw, Xb);

  qkv_gemm<<<dim3(64, 18, 2), 256, 0, stream>>>(Xb, Yb, Wxb, Wyb,
                                                Qx, Kx, Vtx, Qy, Ky, Vty);
  attn_kernel<<<dim3(8, 96, 2), 256, 0, stream>>>(Qx, Kx, Vtx, Qy, Ky, Vty, Ox, Oy);
  proj_gemm<<<dim3(64, 6, 2), 256, 0, stream>>>(Ox, Oy, Pxb, Pyb, xpb, ypb, out);
}

// Round 3
// 305.324 us; speedup vs baseline: 1.2486x; 1.0338x over previous
//
#include <hip/hip_runtime.h>
#include <stdint.h>
#include <stddef.h>

typedef unsigned short u16;
typedef __attribute__((ext_vector_type(8))) short bf16x8;
typedef __attribute__((ext_vector_type(4))) float f32x4;
typedef __attribute__((ext_vector_type(4))) unsigned short u16x4;

#define MFMA_BF16 __builtin_amdgcn_mfma_f32_16x16x32_bf16
// raw barrier: wait own vmcnt (own async tile chunk landed) then barrier.
// Prefetch for the NEXT tile is issued AFTER this, so the wait only covers
// loads that flew during a full compute phase.
#define BAR_FULL asm volatile("s_waitcnt vmcnt(0)\n\ts_barrier" ::: "memory")

// round-to-nearest-even fp32 -> bf16
__device__ __forceinline__ u16 f2b(float x) {
  uint32_t u = __builtin_bit_cast(uint32_t, x);
  return (u16)((u + 0x7fffu + ((u >> 16) & 1u)) >> 16);
}

// async global->LDS, 16B per lane. LDS dst is wave-uniform base + lane*16.
__device__ __forceinline__ void async16(const void* g, void* l) {
  __builtin_amdgcn_global_load_lds((const __attribute__((address_space(1))) void*)g,
                                   (__attribute__((address_space(3))) void*)l, 16, 0, 0);
}

// ---------------------------------------------------------------- fused converts
__global__ void cvt_all(const float* __restrict__ x, const float* __restrict__ y,
                        const float* __restrict__ xqw, const float* __restrict__ yqw,
                        const float* __restrict__ xpw, const float* __restrict__ ypw,
                        u16* __restrict__ dst) {
  long i = ((long)blockIdx.x * 256 + threadIdx.x) * 4;
  const float* src;
  long off;
  if (i < 6291456)       { src = x;   off = 0; }
  else if (i < 12582912) { src = y;   off = 6291456; }
  else if (i < 14352384) { src = xqw; off = 12582912; }
  else if (i < 16121856) { src = yqw; off = 14352384; }
  else if (i < 16711680) { src = xpw; off = 16121856; }
  else                   { src = ypw; off = 16711680; }
  float4 v = *(const float4*)(src + (i - off));
  u16x4 o = { f2b(v.x), f2b(v.y), f2b(v.z), f2b(v.w) };
  *(u16x4*)(dst + i) = o;
}

// ---------------------------------------------------------------- QKV GEMM
// C[m,j] = sum_k A[m,k]*W[j,k];  M=8192, Ncols=2304, K=768.
// Double-buffered LDS (64KB), one barrier per K-iter, prefetch issued after
// the barrier. XOR chunk swizzle -> conflict-free ds_read_b128 fragments.
// Epilogue transposes through LDS (reusing the dbuf) for coalesced dwordx4
// stores of Q [b,h,n,d] (x0.125), K [b,h,n,d], V^T [b,h,d,n].
__global__ __launch_bounds__(256, 2)
void qkv_gemm(const u16* __restrict__ Xb, const u16* __restrict__ Yb,
              const u16* __restrict__ Wx, const u16* __restrict__ Wy,
              u16* __restrict__ Qx, u16* __restrict__ Kx, u16* __restrict__ Vtx,
              u16* __restrict__ Qy, u16* __restrict__ Ky, u16* __restrict__ Vty) {
  __shared__ alignas(16) char smem[65536];  // As dbuf [0,32K), Bs dbuf [32K,64K); epilogue Ts[128][136]
  const int br = blockIdx.z;
  const u16* A = br ? Yb : Xb;
  const u16* W = br ? Wy : Wx;
  u16* Qd = br ? Qy : Qx;
  u16* Kd = br ? Ky : Kx;
  u16* Vd = br ? Vty : Vtx;
  const int m0 = blockIdx.x * 128;
  const int j0 = blockIdx.y * 128;
  const int tid = threadIdx.x;
  const int wave = tid >> 6, lane = tid & 63;
  const int quad = lane >> 4, l16 = lane & 15;
  const int wm = wave >> 1, wn = wave & 1;
  const int srow = wave * 32 + (lane >> 3);                 // +c*8
  const int scol = (((lane & 7) ^ ((lane >> 3) & 7)) * 8);  // swizzled chunk
  const int l7 = l16 & 7;

  auto stage = [&](int k0, int p) {
#pragma unroll
    for (int c = 0; c < 4; ++c) {
      async16(A + (size_t)(m0 + srow + c * 8) * 768 + k0 + scol,
              smem + p * 16384 + wave * 4096 + c * 1024);
      async16(W + (size_t)(j0 + srow + c * 8) * 768 + k0 + scol,
              smem + 32768 + p * 16384 + wave * 4096 + c * 1024);
    }
  };

  f32x4 acc[4][4] = {};
  stage(0, 0);

  for (int kt = 0; kt < 12; ++kt) {
    const int p = kt & 1;
    BAR_FULL;
    if (kt < 11) stage((kt + 1) * 64, p ^ 1);
    const u16* Ap = (const u16*)smem + p * 8192;
    const u16* Bp = (const u16*)smem + 16384 + p * 8192;
#pragma unroll
    for (int kc = 0; kc < 2; ++kc) {
      bf16x8 af[4], bfr[4];
#pragma unroll
      for (int t = 0; t < 4; ++t) {
        af[t]  = *(const bf16x8*)&Ap[(wm * 64 + t * 16 + l16) * 64 + (((kc * 4 + quad) ^ l7) * 8)];
        bfr[t] = *(const bf16x8*)&Bp[(wn * 64 + t * 16 + l16) * 64 + (((kc * 4 + quad) ^ l7) * 8)];
      }
#pragma unroll
      for (int mt = 0; mt < 4; ++mt)
#pragma unroll
        for (int nt = 0; nt < 4; ++nt)
          acc[mt][nt] = MFMA_BF16(af[mt], bfr[nt], acc[mt][nt], 0, 0, 0);
    }
  }

  __syncthreads();  // everyone done reading dbuf; safe to reuse as Ts
  u16* Ts = (u16*)smem;  // [128][136]
  const int s3 = j0 / 768;  // 0=Q 1=K 2=V, uniform per block

  if (s3 == 2) {
    // transpose to [j][m] so V^T rows (fixed d, contiguous n) read coalesced
#pragma unroll
    for (int mt = 0; mt < 4; ++mt)
#pragma unroll
      for (int nt = 0; nt < 4; ++nt) {
        const int j = wn * 64 + nt * 16 + l16;
        const int mb = wm * 64 + mt * 16 + quad * 4;
        u16x4 pk = { f2b(acc[mt][nt][0]), f2b(acc[mt][nt][1]),
                     f2b(acc[mt][nt][2]), f2b(acc[mt][nt][3]) };
        *(u16x4*)&Ts[j * 136 + mb] = pk;
      }
    __syncthreads();
#pragma unroll
    for (int rt = 0; rt < 8; ++rt) {
      const int j = wave * 32 + rt * 4 + (lane >> 4);
      const int mo = (lane & 15) * 8;
      bf16x8 v = *(const bf16x8*)&Ts[j * 136 + mo];
      const int jr = j0 + j - 1536;
      const int h = jr >> 6, d = jr & 63;
      const int gm = m0 + mo;
      const int b = gm >> 10, n = gm & 1023;
      *(bf16x8*)&Vd[((size_t)(b * 12 + h) * 64 + d) * 1024 + n] = v;
    }
  } else {
    const float qs = s3 ? 1.0f : 0.125f;
#pragma unroll
    for (int mt = 0; mt < 4; ++mt)
#pragma unroll
      for (int nt = 0; nt < 4; ++nt) {
        const int j = wn * 64 + nt * 16 + l16;
#pragma unroll
        for (int r = 0; r < 4; ++r) {
          const int m = wm * 64 + mt * 16 + quad * 4 + r;
          Ts[m * 136 + j] = f2b(acc[mt][nt][r] * qs);
        }
      }
    __syncthreads();
    u16* Dd = s3 ? Kd : Qd;
#pragma unroll
    for (int rt = 0; rt < 8; ++rt) {
      const int m = wave * 32 + rt * 4 + (lane >> 4);
      const int jh = (lane >> 3) & 1, jo = (lane & 7) * 8;
      bf16x8 v = *(const bf16x8*)&Ts[m * 136 + jh * 64 + jo];
      const int jr = j0 + jh * 64 + jo - s3 * 768;
      const int h = jr >> 6, d = jr & 63;  // d == jo
      const int gm = m0 + m;
      const int b = gm >> 10, n = gm & 1023;
      *(bf16x8*)&Dd[((size_t)(b * 12 + h) * 1024 + n) * 64 + d] = v;
    }
  }
}

// ---------------------------------------------------------------- flash attention
__global__ __launch_bounds__(256, 3)
void attn_kernel(const u16* __restrict__ Qx, const u16* __restrict__ Kx, const u16* __restrict__ Vtx,
                 const u16* __restrict__ Qy, const u16* __restrict__ Ky, const u16* __restrict__ Vty,
                 u16* __restrict__ Ox, u16* __restrict__ Oy) {
  __shared__ alignas(16) u16 Ks[2][64 * 64];   // [kv][d], swizzled
  __shared__ alignas(16) u16 Vs[2][64 * 64];   // [d][kv], swizzled
  __shared__ alignas(16) u16 Ps[128 * 72];     // [q][kv], padded +8
  const int br = blockIdx.z;
  const u16* Q = br ? Qy : Qx;
  const u16* K = br ? Ky : Kx;
  const u16* V = br ? Vtx : Vty;  // swapped-V cross attention
  u16* O = br ? Oy : Ox;
  const int bh = blockIdx.y;
  const int q0 = blockIdx.x * 128;
  const int tid = threadIdx.x;
  const int wave = tid >> 6, lane = tid & 63;
  const int quad = lane >> 4, l16 = lane & 15;
  const int l7 = l16 & 7;
  const int r8 = (lane >> 3) & 7;
  const int sw = ((lane & 7) ^ r8) * 8;        // swizzled chunk (u16 offset)

  const u16* Qb = Q + (size_t)bh * 65536;
  const u16* Kb = K + (size_t)bh * 65536;
  const u16* Vb = V + (size_t)bh * 65536;

  bf16x8 qf[2][2];
#pragma unroll
  for (int mt = 0; mt < 2; ++mt)
#pragma unroll
    for (int kc = 0; kc < 2; ++kc)
      qf[mt][kc] = *(const bf16x8*)(Qb + (size_t)(q0 + wave * 32 + mt * 16 + l16) * 64 + kc * 32 + quad * 8);

  f32x4 oacc[2][4] = {};
  f32x4 lsum[2] = {};
  bf16x8 ones;
#pragma unroll
  for (int j = 0; j < 8; ++j) ones[j] = (short)0x3f80;  // 1.0bf16

  const int krow = wave * 16 + r8;

#pragma unroll
  for (int c = 0; c < 2; ++c) {
    async16(Kb + (size_t)(krow + c * 8) * 64 + sw, (char*)Ks[0] + wave * 2048 + c * 1024);
    async16(Vb + (size_t)(krow + c * 8) * 1024 + sw, (char*)Vs[0] + wave * 2048 + c * 1024);
  }

  for (int it = 0; it < 16; ++it) {
    const int p = it & 1;
    BAR_FULL;
    if (it < 15) {
      const int kv1 = (it + 1) * 64;
#pragma unroll
      for (int c = 0; c < 2; ++c) {
        async16(Kb + (size_t)(kv1 + krow + c * 8) * 64 + sw, (char*)Ks[p ^ 1] + wave * 2048 + c * 1024);
        async16(Vb + (size_t)(krow + c * 8) * 1024 + kv1 + sw, (char*)Vs[p ^ 1] + wave * 2048 + c * 1024);
      }
    }

    // S = Q K^T
    f32x4 sc[2][4] = {};
#pragma unroll
    for (int kc = 0; kc < 2; ++kc) {
      bf16x8 kf[4];
#pragma unroll
      for (int nt = 0; nt < 4; ++nt)
        kf[nt] = *(const bf16x8*)&Ks[p][(nt * 16 + l16) * 64 + (((kc * 4 + quad) ^ l7) * 8)];
#pragma unroll
      for (int mt = 0; mt < 2; ++mt)
#pragma unroll
        for (int nt = 0; nt < 4; ++nt)
          sc[mt][nt] = MFMA_BF16(qf[mt][kc], kf[nt], sc[mt][nt], 0, 0, 0);
    }

    // P = exp(S) -> Ps (own rows only; no barrier needed)
#pragma unroll
    for (int mt = 0; mt < 2; ++mt) {
      const int prow = wave * 32 + mt * 16 + quad * 4;
#pragma unroll
      for (int nt = 0; nt < 4; ++nt) {
        const int pcol = nt * 16 + l16;
#pragma unroll
        for (int r = 0; r < 4; ++r)
          Ps[(prow + r) * 72 + pcol] = f2b(__expf(sc[mt][nt][r]));
      }
    }

    // O += P @ V ; lsum += P @ ones  (row sums on the matrix pipe)
#pragma unroll
    for (int kc = 0; kc < 2; ++kc) {
      bf16x8 pf[2], vf[4];
#pragma unroll
      for (int mt = 0; mt < 2; ++mt)
        pf[mt] = *(const bf16x8*)&Ps[(wave * 32 + mt * 16 + l16) * 72 + kc * 32 + quad * 8];
#pragma unroll
      for (int nt = 0; nt < 4; ++nt)
        vf[nt] = *(const bf16x8*)&Vs[p][(nt * 16 + l16) * 64 + (((kc * 4 + quad) ^ l7) * 8)];
#pragma unroll
      for (int mt = 0; mt < 2; ++mt) {
#pragma unroll
        for (int nt = 0; nt < 4; ++nt)
          oacc[mt][nt] = MFMA_BF16(pf[mt], vf[nt], oacc[mt][nt], 0, 0, 0);
        lsum[mt] = MFMA_BF16(pf[mt], ones, lsum[mt], 0, 0, 0);
      }
    }
  }

  // epilogue: O / l -> bf16 [b, n, h*64+d]
  const int b = bh / 12, h = bh % 12;
#pragma unroll
  for (int mt = 0; mt < 2; ++mt) {
#pragma unroll
    for (int r = 0; r < 4; ++r) {
      const float inv = 1.0f / lsum[mt][r];
      const int qrow = q0 + wave * 32 + mt * 16 + quad * 4 + r;
      const size_t ob = ((size_t)(b * 1024 + qrow)) * 768 + h * 64;
#pragma unroll
      for (int nt = 0; nt < 4; ++nt)
        O[ob + nt * 16 + l16] = f2b(oacc[mt][nt][r] * inv);
    }
  }
}

// ---------------------------------------------------------------- proj GEMM + bias
__global__ __launch_bounds__(256, 2)
void proj_gemm(const u16* __restrict__ Ox, const u16* __restrict__ Oy,
               const u16* __restrict__ Pxw, const u16* __restrict__ Pyw,
               const float* __restrict__ bx, const float* __restrict__ by,
               float* __restrict__ out) {
  __shared__ alignas(16) char smem[65536];
  const int br = blockIdx.z;
  const u16* A = br ? Oy : Ox;
  const u16* W = br ? Pyw : Pxw;
  const float* bias = br ? by : bx;
  float* op = out + (size_t)br * 6291456;
  const int m0 = blockIdx.x * 128;
  const int j0 = blockIdx.y * 128;
  const int tid = threadIdx.x;
  const int wave = tid >> 6, lane = tid & 63;
  const int quad = lane >> 4, l16 = lane & 15;
  const int wm = wave >> 1, wn = wave & 1;
  const int srow = wave * 32 + (lane >> 3);
  const int scol = (((lane & 7) ^ ((lane >> 3) & 7)) * 8);
  const int l7 = l16 & 7;

  auto stage = [&](int k0, int p) {
#pragma unroll
    for (int c = 0; c < 4; ++c) {
      async16(A + (size_t)(m0 + srow + c * 8) * 768 + k0 + scol,
              smem + p * 16384 + wave * 4096 + c * 1024);
      async16(W + (size_t)(j0 + srow + c * 8) * 768 + k0 + scol,
              smem + 32768 + p * 16384 + wave * 4096 + c * 1024);
    }
  };

  f32x4 acc[4][4] = {};
  stage(0, 0);

  for (int kt = 0; kt < 12; ++kt) {
    const int p = kt & 1;
    BAR_FULL;
    if (kt < 11) stage((kt + 1) * 64, p ^ 1);
    const u16* Ap = (const u16*)smem + p * 8192;
    const u16* Bp = (const u16*)smem + 16384 + p * 8192;
#pragma unroll
    for (int kc = 0; kc < 2; ++kc) {
      bf16x8 af[4], bfr[4];
#pragma unroll
      for (int t = 0; t < 4; ++t) {
        af[t]  = *(const bf16x8*)&Ap[(wm * 64 + t * 16 + l16) * 64 + (((kc * 4 + quad) ^ l7) * 8)];
        bfr[t] = *(const bf16x8*)&Bp[(wn * 64 + t * 16 + l16) * 64 + (((kc * 4 + quad) ^ l7) * 8)];
      }
#pragma unroll
      for (int mt = 0; mt < 4; ++mt)
#pragma unroll
        for (int nt = 0; nt < 4; ++nt)
          acc[mt][nt] = MFMA_BF16(af[mt], bfr[nt], acc[mt][nt], 0, 0, 0);
    }
  }

#pragma unroll
  for (int mt = 0; mt < 4; ++mt) {
#pragma unroll
    for (int nt = 0; nt < 4; ++nt) {
      const int j = j0 + wn * 64 + nt * 16 + l16;
      const float bj = bias[j];
#pragma unroll
      for (int r = 0; r < 4; ++r) {
        const int m = m0 + wm * 64 + mt * 16 + quad * 4 + r;
        op[(size_t)m * 768 + j] = acc[mt][nt][r] + bj;
      }
    }
  }
}

// ---------------------------------------------------------------- launch
extern "C" void kernel_launch(void* const* d_in, const int* in_sizes, int n_in,
                              void* d_out, int out_size, void* d_ws, size_t ws_size,
                              hipStream_t stream) {
  (void)in_sizes; (void)n_in; (void)out_size; (void)ws_size;
  const float* x   = (const float*)d_in[0];
  const float* y   = (const float*)d_in[1];
  const float* xqw = (const float*)d_in[2];
  const float* yqw = (const float*)d_in[3];
  const float* xpw = (const float*)d_in[4];
  const float* xpb = (const float*)d_in[5];
  const float* ypw = (const float*)d_in[6];
  const float* ypb = (const float*)d_in[7];
  float* out = (float*)d_out;

  char* p = (char*)d_ws;
  u16* Xb  = (u16*)p; p += 12582912;   // contiguous bf16 block for cvt_all:
  u16* Yb  = (u16*)p; p += 12582912;   // Xb Yb Wxb Wyb Pxb Pyb
  u16* Wxb = (u16*)p; p += 3538944;
  u16* Wyb = (u16*)p; p += 3538944;
  u16* Pxb = (u16*)p; p += 1179648;
  u16* Pyb = (u16*)p; p += 1179648;
  u16* Qx  = (u16*)p; p += 12582912;   // [b,h,n,d] bf16 (pre-scaled)
  u16* Kx  = (u16*)p; p += 12582912;
  u16* Vtx = (u16*)p; p += 12582912;   // [b,h,d,n] bf16
  u16* Qy  = (u16*)p; p += 12582912;
  u16* Ky  = (u16*)p; p += 12582912;
  u16* Vty = (u16*)p; p += 12582912;
  u16* Ox  = Xb;  // alias: Xb/Yb dead after qkv_gemm (stream-ordered)
  u16* Oy  = Yb;

  cvt_all<<<16896, 256, 0, stream>>>(x, y, xqw, yqw, xpw, ypw, Xb);

  qkv_gemm<<<dim3(64, 18, 2), 256, 0, stream>>>(Xb, Yb, Wxb, Wyb,
                                                Qx, Kx, Vtx, Qy, Ky, Vty);
  attn_kernel<<<dim3(8, 96, 2), 256, 0, stream>>>(Qx, Kx, Vtx, Qy, Ky, Vty, Ox, Oy);
  proj_gemm<<<dim3(64, 6, 2), 256, 0, stream>>>(Ox, Oy, Pxb, Pyb, xpb, ypb, out);
}

// Round 4
// 277.272 us; speedup vs baseline: 1.3750x; 1.1012x over previous
//
#include <hip/hip_runtime.h>
#include <hip/hip_bf16.h>
#include <stdint.h>
#include <stddef.h>

typedef unsigned short u16;
typedef __attribute__((ext_vector_type(8))) short bf16x8;
typedef __attribute__((ext_vector_type(4))) short bf16x4;
typedef __attribute__((ext_vector_type(4))) float f32x4;
typedef __attribute__((ext_vector_type(4))) unsigned short u16x4;

#define MFMA_BF16 __builtin_amdgcn_mfma_f32_16x16x32_bf16

#if defined(__has_builtin)
#if __has_builtin(__builtin_amdgcn_mfma_f32_16x16x16bf16_1k)
#define MFMA16(a, b, c) __builtin_amdgcn_mfma_f32_16x16x16bf16_1k(a, b, c, 0, 0, 0)
#endif
#endif
#ifndef MFMA16
__device__ __forceinline__ f32x4 mfma16_asm(bf16x4 a, bf16x4 b, f32x4 c) {
  asm volatile("s_nop 1\n\tv_mfma_f32_16x16x16_bf16 %0, %1, %2, %0\n\ts_nop 7\n\ts_nop 7"
               : "+v"(c) : "v"(a), "v"(b));
  return c;
}
#define MFMA16(a, b, c) mfma16_asm(a, b, c)
#endif

// raw barrier: wait own vmcnt (own async tile chunk landed) then barrier.
// Prefetch for the NEXT tile is issued AFTER this, so the wait only covers
// loads that flew during a full compute phase.
#define BAR_FULL asm volatile("s_waitcnt vmcnt(0)\n\ts_barrier" ::: "memory")

// round-to-nearest-even fp32 -> bf16
__device__ __forceinline__ u16 f2b(float x) {
  uint32_t u = __builtin_bit_cast(uint32_t, x);
  return (u16)((u + 0x7fffu + ((u >> 16) & 1u)) >> 16);
}

// packed fp32x4 -> bf16x4 (v_cvt_pk_bf16_f32 x2)
__device__ __forceinline__ bf16x4 pack4(float a, float b, float c, float d) {
  union { __hip_bfloat162 h[2]; bf16x4 v; } u;
  u.h[0] = __float22bfloat162_rn(make_float2(a, b));
  u.h[1] = __float22bfloat162_rn(make_float2(c, d));
  return u.v;
}

// async global->LDS, 16B per lane. LDS dst is wave-uniform base + lane*16.
__device__ __forceinline__ void async16(const void* g, void* l) {
  __builtin_amdgcn_global_load_lds((const __attribute__((address_space(1))) void*)g,
                                   (__attribute__((address_space(3))) void*)l, 16, 0, 0);
}

// ---------------------------------------------------------------- fused converts
__global__ void cvt_all(const float* __restrict__ x, const float* __restrict__ y,
                        const float* __restrict__ xqw, const float* __restrict__ yqw,
                        const float* __restrict__ xpw, const float* __restrict__ ypw,
                        u16* __restrict__ dst) {
  long i = ((long)blockIdx.x * 256 + threadIdx.x) * 4;
  const float* src;
  long off;
  if (i < 6291456)       { src = x;   off = 0; }
  else if (i < 12582912) { src = y;   off = 6291456; }
  else if (i < 14352384) { src = xqw; off = 12582912; }
  else if (i < 16121856) { src = yqw; off = 14352384; }
  else if (i < 16711680) { src = xpw; off = 16121856; }
  else                   { src = ypw; off = 16711680; }
  float4 v = *(const float4*)(src + (i - off));
  u16x4 o = { f2b(v.x), f2b(v.y), f2b(v.z), f2b(v.w) };
  *(u16x4*)(dst + i) = o;
}

// ---------------------------------------------------------------- QKV GEMM
__global__ __launch_bounds__(256, 2)
void qkv_gemm(const u16* __restrict__ Xb, const u16* __restrict__ Yb,
              const u16* __restrict__ Wx, const u16* __restrict__ Wy,
              u16* __restrict__ Qx, u16* __restrict__ Kx, u16* __restrict__ Vtx,
              u16* __restrict__ Qy, u16* __restrict__ Ky, u16* __restrict__ Vty) {
  __shared__ alignas(16) char smem[65536];  // As dbuf [0,32K), Bs dbuf [32K,64K); epilogue Ts[128][136]
  const int br = blockIdx.z;
  const u16* A = br ? Yb : Xb;
  const u16* W = br ? Wy : Wx;
  u16* Qd = br ? Qy : Qx;
  u16* Kd = br ? Ky : Kx;
  u16* Vd = br ? Vty : Vtx;
  const int m0 = blockIdx.x * 128;
  const int j0 = blockIdx.y * 128;
  const int tid = threadIdx.x;
  const int wave = tid >> 6, lane = tid & 63;
  const int quad = lane >> 4, l16 = lane & 15;
  const int wm = wave >> 1, wn = wave & 1;
  const int srow = wave * 32 + (lane >> 3);                 // +c*8
  const int scol = (((lane & 7) ^ ((lane >> 3) & 7)) * 8);  // swizzled chunk
  const int l7 = l16 & 7;

  auto stage = [&](int k0, int p) {
#pragma unroll
    for (int c = 0; c < 4; ++c) {
      async16(A + (size_t)(m0 + srow + c * 8) * 768 + k0 + scol,
              smem + p * 16384 + wave * 4096 + c * 1024);
      async16(W + (size_t)(j0 + srow + c * 8) * 768 + k0 + scol,
              smem + 32768 + p * 16384 + wave * 4096 + c * 1024);
    }
  };

  f32x4 acc[4][4] = {};
  stage(0, 0);

  for (int kt = 0; kt < 12; ++kt) {
    const int p = kt & 1;
    BAR_FULL;
    if (kt < 11) stage((kt + 1) * 64, p ^ 1);
    const u16* Ap = (const u16*)smem + p * 8192;
    const u16* Bp = (const u16*)smem + 16384 + p * 8192;
#pragma unroll
    for (int kc = 0; kc < 2; ++kc) {
      bf16x8 af[4], bfr[4];
#pragma unroll
      for (int t = 0; t < 4; ++t) {
        af[t]  = *(const bf16x8*)&Ap[(wm * 64 + t * 16 + l16) * 64 + (((kc * 4 + quad) ^ l7) * 8)];
        bfr[t] = *(const bf16x8*)&Bp[(wn * 64 + t * 16 + l16) * 64 + (((kc * 4 + quad) ^ l7) * 8)];
      }
#pragma unroll
      for (int mt = 0; mt < 4; ++mt)
#pragma unroll
        for (int nt = 0; nt < 4; ++nt)
          acc[mt][nt] = MFMA_BF16(af[mt], bfr[nt], acc[mt][nt], 0, 0, 0);
    }
  }

  __syncthreads();  // everyone done reading dbuf; safe to reuse as Ts
  u16* Ts = (u16*)smem;  // [128][136]
  const int s3 = j0 / 768;  // 0=Q 1=K 2=V, uniform per block

  if (s3 == 2) {
    // transpose to [j][m] so V^T rows (fixed d, contiguous n) read coalesced
#pragma unroll
    for (int mt = 0; mt < 4; ++mt)
#pragma unroll
      for (int nt = 0; nt < 4; ++nt) {
        const int j = wn * 64 + nt * 16 + l16;
        const int mb = wm * 64 + mt * 16 + quad * 4;
        u16x4 pk = { f2b(acc[mt][nt][0]), f2b(acc[mt][nt][1]),
                     f2b(acc[mt][nt][2]), f2b(acc[mt][nt][3]) };
        *(u16x4*)&Ts[j * 136 + mb] = pk;
      }
    __syncthreads();
#pragma unroll
    for (int rt = 0; rt < 8; ++rt) {
      const int j = wave * 32 + rt * 4 + (lane >> 4);
      const int mo = (lane & 15) * 8;
      bf16x8 v = *(const bf16x8*)&Ts[j * 136 + mo];
      const int jr = j0 + j - 1536;
      const int h = jr >> 6, d = jr & 63;
      const int gm = m0 + mo;
      const int b = gm >> 10, n = gm & 1023;
      *(bf16x8*)&Vd[((size_t)(b * 12 + h) * 64 + d) * 1024 + n] = v;
    }
  } else {
    const float qs = s3 ? 1.0f : 0.125f;
#pragma unroll
    for (int mt = 0; mt < 4; ++mt)
#pragma unroll
      for (int nt = 0; nt < 4; ++nt) {
        const int j = wn * 64 + nt * 16 + l16;
#pragma unroll
        for (int r = 0; r < 4; ++r) {
          const int m = wm * 64 + mt * 16 + quad * 4 + r;
          Ts[m * 136 + j] = f2b(acc[mt][nt][r] * qs);
        }
      }
    __syncthreads();
    u16* Dd = s3 ? Kd : Qd;
#pragma unroll
    for (int rt = 0; rt < 8; ++rt) {
      const int m = wave * 32 + rt * 4 + (lane >> 4);
      const int jh = (lane >> 3) & 1, jo = (lane & 7) * 8;
      bf16x8 v = *(const bf16x8*)&Ts[m * 136 + jh * 64 + jo];
      const int jr = j0 + jh * 64 + jo - s3 * 768;
      const int h = jr >> 6, d = jr & 63;  // d == jo
      const int gm = m0 + m;
      const int b = gm >> 10, n = gm & 1023;
      *(bf16x8*)&Dd[((size_t)(b * 12 + h) * 1024 + n) * 64 + d] = v;
    }
  }
}

// ---------------------------------------------------------------- flash attention
// S^T trick: QK^T computed as MFMA(A=K,B=Q) -> S^T C-layout gives each lane
// q=l16, kv=quad*4+r, which IS the A-operand layout of the K=16 MFMA. So
// P=exp(S^T) feeds PV (and the ones-rowsum) directly from registers — no LDS
// round-trip for P at all. LDS = K/V dbuf only (32KB) -> 4+ blocks/CU.
__global__ __launch_bounds__(256, 4)
void attn_kernel(const u16* __restrict__ Qx, const u16* __restrict__ Kx, const u16* __restrict__ Vtx,
                 const u16* __restrict__ Qy, const u16* __restrict__ Ky, const u16* __restrict__ Vty,
                 u16* __restrict__ Ox, u16* __restrict__ Oy) {
  __shared__ alignas(16) u16 Ks[2][64 * 64];   // [kv][d], 16B-chunk swizzled
  __shared__ alignas(16) u16 Vs[2][64 * 64];   // [d][kv], 16B-chunk swizzled
  const int br = blockIdx.z;
  const u16* Q = br ? Qy : Qx;
  const u16* K = br ? Ky : Kx;
  const u16* V = br ? Vtx : Vty;  // swapped-V cross attention
  u16* O = br ? Oy : Ox;
  const int bh = blockIdx.y;
  const int q0 = blockIdx.x * 128;
  const int tid = threadIdx.x;
  const int wave = tid >> 6, lane = tid & 63;
  const int quad = lane >> 4, l16 = lane & 15;
  const int l7 = l16 & 7;
  const int r8 = (lane >> 3) & 7;
  const int sw = ((lane & 7) ^ r8) * 8;        // swizzled chunk (u16 offset)

  const u16* Qb = Q + (size_t)bh * 65536;
  const u16* Kb = K + (size_t)bh * 65536;
  const u16* Vb = V + (size_t)bh * 65536;

  // loop-invariant Q fragments (B-operand role; same per-lane data as A-layout)
  bf16x8 qf[2][2];
#pragma unroll
  for (int mt = 0; mt < 2; ++mt)
#pragma unroll
    for (int kc = 0; kc < 2; ++kc)
      qf[mt][kc] = *(const bf16x8*)(Qb + (size_t)(q0 + wave * 32 + mt * 16 + l16) * 64 + kc * 32 + quad * 8);

  f32x4 oacc[2][4] = {};
  f32x4 lsum[2] = {};
  bf16x4 ones4;
#pragma unroll
  for (int j = 0; j < 4; ++j) ones4[j] = (short)0x3f80;  // 1.0bf16

  const int krow = wave * 16 + r8;

#pragma unroll
  for (int c = 0; c < 2; ++c) {
    async16(Kb + (size_t)(krow + c * 8) * 64 + sw, (char*)Ks[0] + wave * 2048 + c * 1024);
    async16(Vb + (size_t)(krow + c * 8) * 1024 + sw, (char*)Vs[0] + wave * 2048 + c * 1024);
  }

  for (int it = 0; it < 16; ++it) {
    const int p = it & 1;
    BAR_FULL;
    if (it < 15) {
      const int kv1 = (it + 1) * 64;
#pragma unroll
      for (int c = 0; c < 2; ++c) {
        async16(Kb + (size_t)(kv1 + krow + c * 8) * 64 + sw, (char*)Ks[p ^ 1] + wave * 2048 + c * 1024);
        async16(Vb + (size_t)(krow + c * 8) * 1024 + kv1 + sw, (char*)Vs[p ^ 1] + wave * 2048 + c * 1024);
      }
    }

    // S^T = K Q^T : st[kt][mt], lane holds q=l16, kv=kt*16+quad*4+r
    f32x4 st[4][2] = {};
    const u16* Kp = Ks[p];
#pragma unroll
    for (int kc = 0; kc < 2; ++kc) {
      bf16x8 kf[4];
#pragma unroll
      for (int kt = 0; kt < 4; ++kt)
        kf[kt] = *(const bf16x8*)&Kp[(kt * 16 + l16) * 64 + (((kc * 4 + quad) ^ l7) * 8)];
#pragma unroll
      for (int kt = 0; kt < 4; ++kt)
#pragma unroll
        for (int mt = 0; mt < 2; ++mt)
          st[kt][mt] = MFMA_BF16(kf[kt], qf[mt][kc], st[kt][mt], 0, 0, 0);
    }

    // P = exp(S^T), packed straight into K=16 A-operand fragments
    bf16x4 pf[4][2];
#pragma unroll
    for (int kt = 0; kt < 4; ++kt)
#pragma unroll
      for (int mt = 0; mt < 2; ++mt)
        pf[kt][mt] = pack4(__expf(st[kt][mt][0]), __expf(st[kt][mt][1]),
                           __expf(st[kt][mt][2]), __expf(st[kt][mt][3]));

    // O += P @ V ; lsum += P @ ones  (all on the matrix pipe, K=16 steps)
    const u16* Vp = Vs[p];
#pragma unroll
    for (int kt = 0; kt < 4; ++kt) {
      bf16x4 vf[4];
      const int c16 = kt * 2 + (quad >> 1);
      const int hh = (quad & 1) * 4;
#pragma unroll
      for (int dt = 0; dt < 4; ++dt)
        vf[dt] = *(const bf16x4*)&Vp[(dt * 16 + l16) * 64 + ((c16 ^ l7) * 8) + hh];
#pragma unroll
      for (int mt = 0; mt < 2; ++mt) {
#pragma unroll
        for (int dt = 0; dt < 4; ++dt)
          oacc[mt][dt] = MFMA16(pf[kt][mt], vf[dt], oacc[mt][dt]);
        lsum[mt] = MFMA16(pf[kt][mt], ones4, lsum[mt]);
      }
    }
  }

  // epilogue: O / l -> bf16 [b, n, h*64+d]
  const int b = bh / 12, h = bh % 12;
#pragma unroll
  for (int mt = 0; mt < 2; ++mt) {
#pragma unroll
    for (int r = 0; r < 4; ++r) {
      const float inv = 1.0f / lsum[mt][r];
      const int qrow = q0 + wave * 32 + mt * 16 + quad * 4 + r;
      const size_t ob = ((size_t)(b * 1024 + qrow)) * 768 + h * 64;
#pragma unroll
      for (int nt = 0; nt < 4; ++nt)
        O[ob + nt * 16 + l16] = f2b(oacc[mt][nt][r] * inv);
    }
  }
}

// ---------------------------------------------------------------- proj GEMM + bias
__global__ __launch_bounds__(256, 2)
void proj_gemm(const u16* __restrict__ Ox, const u16* __restrict__ Oy,
               const u16* __restrict__ Pxw, const u16* __restrict__ Pyw,
               const float* __restrict__ bx, const float* __restrict__ by,
               float* __restrict__ out) {
  __shared__ alignas(16) char smem[65536];
  const int br = blockIdx.z;
  const u16* A = br ? Oy : Ox;
  const u16* W = br ? Pyw : Pxw;
  const float* bias = br ? by : bx;
  float* op = out + (size_t)br * 6291456;
  const int m0 = blockIdx.x * 128;
  const int j0 = blockIdx.y * 128;
  const int tid = threadIdx.x;
  const int wave = tid >> 6, lane = tid & 63;
  const int quad = lane >> 4, l16 = lane & 15;
  const int wm = wave >> 1, wn = wave & 1;
  const int srow = wave * 32 + (lane >> 3);
  const int scol = (((lane & 7) ^ ((lane >> 3) & 7)) * 8);
  const int l7 = l16 & 7;

  auto stage = [&](int k0, int p) {
#pragma unroll
    for (int c = 0; c < 4; ++c) {
      async16(A + (size_t)(m0 + srow + c * 8) * 768 + k0 + scol,
              smem + p * 16384 + wave * 4096 + c * 1024);
      async16(W + (size_t)(j0 + srow + c * 8) * 768 + k0 + scol,
              smem + 32768 + p * 16384 + wave * 4096 + c * 1024);
    }
  };

  f32x4 acc[4][4] = {};
  stage(0, 0);

  for (int kt = 0; kt < 12; ++kt) {
    const int p = kt & 1;
    BAR_FULL;
    if (kt < 11) stage((kt + 1) * 64, p ^ 1);
    const u16* Ap = (const u16*)smem + p * 8192;
    const u16* Bp = (const u16*)smem + 16384 + p * 8192;
#pragma unroll
    for (int kc = 0; kc < 2; ++kc) {
      bf16x8 af[4], bfr[4];
#pragma unroll
      for (int t = 0; t < 4; ++t) {
        af[t]  = *(const bf16x8*)&Ap[(wm * 64 + t * 16 + l16) * 64 + (((kc * 4 + quad) ^ l7) * 8)];
        bfr[t] = *(const bf16x8*)&Bp[(wn * 64 + t * 16 + l16) * 64 + (((kc * 4 + quad) ^ l7) * 8)];
      }
#pragma unroll
      for (int mt = 0; mt < 4; ++mt)
#pragma unroll
        for (int nt = 0; nt < 4; ++nt)
          acc[mt][nt] = MFMA_BF16(af[mt], bfr[nt], acc[mt][nt], 0, 0, 0);
    }
  }

#pragma unroll
  for (int mt = 0; mt < 4; ++mt) {
#pragma unroll
    for (int nt = 0; nt < 4; ++nt) {
      const int j = j0 + wn * 64 + nt * 16 + l16;
      const float bj = bias[j];
#pragma unroll
      for (int r = 0; r < 4; ++r) {
        const int m = m0 + wm * 64 + mt * 16 + quad * 4 + r;
        op[(size_t)m * 768 + j] = acc[mt][nt][r] + bj;
      }
    }
  }
}

// ---------------------------------------------------------------- launch
extern "C" void kernel_launch(void* const* d_in, const int* in_sizes, int n_in,
                              void* d_out, int out_size, void* d_ws, size_t ws_size,
                              hipStream_t stream) {
  (void)in_sizes; (void)n_in; (void)out_size; (void)ws_size;
  const float* x   = (const float*)d_in[0];
  const float* y   = (const float*)d_in[1];
  const float* xqw = (const float*)d_in[2];
  const float* yqw = (const float*)d_in[3];
  const float* xpw = (const float*)d_in[4];
  const float* xpb = (const float*)d_in[5];
  const float* ypw = (const float*)d_in[6];
  const float* ypb = (const float*)d_in[7];
  float* out = (float*)d_out;

  char* p = (char*)d_ws;
  u16* Xb  = (u16*)p; p += 12582912;   // contiguous bf16 block for cvt_all:
  u16* Yb  = (u16*)p; p += 12582912;   // Xb Yb Wxb Wyb Pxb Pyb
  u16* Wxb = (u16*)p; p += 3538944;
  u16* Wyb = (u16*)p; p += 3538944;
  u16* Pxb = (u16*)p; p += 1179648;
  u16* Pyb = (u16*)p; p += 1179648;
  u16* Qx  = (u16*)p; p += 12582912;   // [b,h,n,d] bf16 (pre-scaled)
  u16* Kx  = (u16*)p; p += 12582912;
  u16* Vtx = (u16*)p; p += 12582912;   // [b,h,d,n] bf16
  u16* Qy  = (u16*)p; p += 12582912;
  u16* Ky  = (u16*)p; p += 12582912;
  u16* Vty = (u16*)p; p += 12582912;
  u16* Ox  = Xb;  // alias: Xb/Yb dead after qkv_gemm (stream-ordered)
  u16* Oy  = Yb;

  cvt_all<<<16896, 256, 0, stream>>>(x, y, xqw, yqw, xpw, ypw, Xb);

  qkv_gemm<<<dim3(64, 18, 2), 256, 0, stream>>>(Xb, Yb, Wxb, Wyb,
                                                Qx, Kx, Vtx, Qy, Ky, Vty);
  attn_kernel<<<dim3(8, 96, 2), 256, 0, stream>>>(Qx, Kx, Vtx, Qy, Ky, Vty, Ox, Oy);
  proj_gemm<<<dim3(64, 6, 2), 256, 0, stream>>>(Ox, Oy, Pxb, Pyb, xpb, ypb, out);
}

// Round 5
// 275.738 us; speedup vs baseline: 1.3826x; 1.0056x over previous
//
#include <hip/hip_runtime.h>
#include <hip/hip_bf16.h>
#include <stdint.h>
#include <stddef.h>

typedef unsigned short u16;
typedef __attribute__((ext_vector_type(8))) short bf16x8;
typedef __attribute__((ext_vector_type(4))) short bf16x4;
typedef __attribute__((ext_vector_type(4))) float f32x4;
typedef __attribute__((ext_vector_type(4))) unsigned short u16x4;

#define MFMA_BF16 __builtin_amdgcn_mfma_f32_16x16x32_bf16

#if defined(__has_builtin)
#if __has_builtin(__builtin_amdgcn_mfma_f32_16x16x16bf16_1k)
#define MFMA16(a, b, c) __builtin_amdgcn_mfma_f32_16x16x16bf16_1k(a, b, c, 0, 0, 0)
#endif
#endif
#ifndef MFMA16
__device__ __forceinline__ f32x4 mfma16_asm(bf16x4 a, bf16x4 b, f32x4 c) {
  asm volatile("s_nop 1\n\tv_mfma_f32_16x16x16_bf16 %0, %1, %2, %0\n\ts_nop 7\n\ts_nop 7"
               : "+v"(c) : "v"(a), "v"(b));
  return c;
}
#define MFMA16(a, b, c) mfma16_asm(a, b, c)
#endif

// exp2 on the hardware transcendental unit (v_exp_f32 IS 2^x)
#if defined(__has_builtin)
#if __has_builtin(__builtin_amdgcn_exp2f)
#define EXP2F(x) __builtin_amdgcn_exp2f(x)
#endif
#endif
#ifndef EXP2F
#define EXP2F(x) __expf((x) * 0.6931471805599453f)
#endif

// raw barrier: wait own vmcnt (own async tile chunk landed) then barrier.
// Prefetch for the NEXT tile is issued AFTER this, so the wait only covers
// loads that flew during a full compute phase.
#define BAR_FULL asm volatile("s_waitcnt vmcnt(0)\n\ts_barrier" ::: "memory")

// Q pre-scale: HEAD_DIM^-0.5 * log2(e), so attention uses exp2 directly.
#define QSCALE 0.18033688011112042f

// round-to-nearest-even fp32 -> bf16
__device__ __forceinline__ u16 f2b(float x) {
  uint32_t u = __builtin_bit_cast(uint32_t, x);
  return (u16)((u + 0x7fffu + ((u >> 16) & 1u)) >> 16);
}

// packed fp32x4 -> bf16x4 (v_cvt_pk_bf16_f32 x2)
__device__ __forceinline__ bf16x4 pack4(float a, float b, float c, float d) {
  union { __hip_bfloat162 h[2]; bf16x4 v; } u;
  u.h[0] = __float22bfloat162_rn(make_float2(a, b));
  u.h[1] = __float22bfloat162_rn(make_float2(c, d));
  return u.v;
}

// async global->LDS, 16B per lane. LDS dst is wave-uniform base + lane*16.
__device__ __forceinline__ void async16(const void* g, void* l) {
  __builtin_amdgcn_global_load_lds((const __attribute__((address_space(1))) void*)g,
                                   (__attribute__((address_space(3))) void*)l, 16, 0, 0);
}

// ---------------------------------------------------------------- fused converts
__global__ void cvt_all(const float* __restrict__ x, const float* __restrict__ y,
                        const float* __restrict__ xqw, const float* __restrict__ yqw,
                        const float* __restrict__ xpw, const float* __restrict__ ypw,
                        u16* __restrict__ dst) {
  long i = ((long)blockIdx.x * 256 + threadIdx.x) * 4;
  const float* src;
  long off;
  if (i < 6291456)       { src = x;   off = 0; }
  else if (i < 12582912) { src = y;   off = 6291456; }
  else if (i < 14352384) { src = xqw; off = 12582912; }
  else if (i < 16121856) { src = yqw; off = 14352384; }
  else if (i < 16711680) { src = xpw; off = 16121856; }
  else                   { src = ypw; off = 16711680; }
  float4 v = *(const float4*)(src + (i - off));
  u16x4 o = { f2b(v.x), f2b(v.y), f2b(v.z), f2b(v.w) };
  *(u16x4*)(dst + i) = o;
}

// ---------------------------------------------------------------- QKV GEMM
__global__ __launch_bounds__(256, 2)
void qkv_gemm(const u16* __restrict__ Xb, const u16* __restrict__ Yb,
              const u16* __restrict__ Wx, const u16* __restrict__ Wy,
              u16* __restrict__ Qx, u16* __restrict__ Kx, u16* __restrict__ Vtx,
              u16* __restrict__ Qy, u16* __restrict__ Ky, u16* __restrict__ Vty) {
  __shared__ alignas(16) char smem[65536];  // As dbuf [0,32K), Bs dbuf [32K,64K); epilogue Ts[128][136]
  const int br = blockIdx.z;
  const u16* A = br ? Yb : Xb;
  const u16* W = br ? Wy : Wx;
  u16* Qd = br ? Qy : Qx;
  u16* Kd = br ? Ky : Kx;
  u16* Vd = br ? Vty : Vtx;
  const int m0 = blockIdx.x * 128;
  const int j0 = blockIdx.y * 128;
  const int tid = threadIdx.x;
  const int wave = tid >> 6, lane = tid & 63;
  const int quad = lane >> 4, l16 = lane & 15;
  const int wm = wave >> 1, wn = wave & 1;
  const int srow = wave * 32 + (lane >> 3);                 // +c*8
  const int scol = (((lane & 7) ^ ((lane >> 3) & 7)) * 8);  // swizzled chunk
  const int l7 = l16 & 7;

  auto stage = [&](int k0, int p) {
#pragma unroll
    for (int c = 0; c < 4; ++c) {
      async16(A + (size_t)(m0 + srow + c * 8) * 768 + k0 + scol,
              smem + p * 16384 + wave * 4096 + c * 1024);
      async16(W + (size_t)(j0 + srow + c * 8) * 768 + k0 + scol,
              smem + 32768 + p * 16384 + wave * 4096 + c * 1024);
    }
  };

  f32x4 acc[4][4] = {};
  stage(0, 0);

  for (int kt = 0; kt < 12; ++kt) {
    const int p = kt & 1;
    BAR_FULL;
    if (kt < 11) stage((kt + 1) * 64, p ^ 1);
    const u16* Ap = (const u16*)smem + p * 8192;
    const u16* Bp = (const u16*)smem + 16384 + p * 8192;
#pragma unroll
    for (int kc = 0; kc < 2; ++kc) {
      bf16x8 af[4], bfr[4];
#pragma unroll
      for (int t = 0; t < 4; ++t) {
        af[t]  = *(const bf16x8*)&Ap[(wm * 64 + t * 16 + l16) * 64 + (((kc * 4 + quad) ^ l7) * 8)];
        bfr[t] = *(const bf16x8*)&Bp[(wn * 64 + t * 16 + l16) * 64 + (((kc * 4 + quad) ^ l7) * 8)];
      }
#pragma unroll
      for (int mt = 0; mt < 4; ++mt)
#pragma unroll
        for (int nt = 0; nt < 4; ++nt)
          acc[mt][nt] = MFMA_BF16(af[mt], bfr[nt], acc[mt][nt], 0, 0, 0);
    }
  }

  __syncthreads();  // everyone done reading dbuf; safe to reuse as Ts
  u16* Ts = (u16*)smem;  // [128][136]
  const int s3 = j0 / 768;  // 0=Q 1=K 2=V, uniform per block

  if (s3 == 2) {
    // transpose to [j][m] so V^T rows (fixed d, contiguous n) read coalesced
#pragma unroll
    for (int mt = 0; mt < 4; ++mt)
#pragma unroll
      for (int nt = 0; nt < 4; ++nt) {
        const int j = wn * 64 + nt * 16 + l16;
        const int mb = wm * 64 + mt * 16 + quad * 4;
        u16x4 pk = { f2b(acc[mt][nt][0]), f2b(acc[mt][nt][1]),
                     f2b(acc[mt][nt][2]), f2b(acc[mt][nt][3]) };
        *(u16x4*)&Ts[j * 136 + mb] = pk;
      }
    __syncthreads();
#pragma unroll
    for (int rt = 0; rt < 8; ++rt) {
      const int j = wave * 32 + rt * 4 + (lane >> 4);
      const int mo = (lane & 15) * 8;
      bf16x8 v = *(const bf16x8*)&Ts[j * 136 + mo];
      const int jr = j0 + j - 1536;
      const int h = jr >> 6, d = jr & 63;
      const int gm = m0 + mo;
      const int b = gm >> 10, n = gm & 1023;
      *(bf16x8*)&Vd[((size_t)(b * 12 + h) * 64 + d) * 1024 + n] = v;
    }
  } else {
    const float qs = s3 ? 1.0f : QSCALE;
#pragma unroll
    for (int mt = 0; mt < 4; ++mt)
#pragma unroll
      for (int nt = 0; nt < 4; ++nt) {
        const int j = wn * 64 + nt * 16 + l16;
#pragma unroll
        for (int r = 0; r < 4; ++r) {
          const int m = wm * 64 + mt * 16 + quad * 4 + r;
          Ts[m * 136 + j] = f2b(acc[mt][nt][r] * qs);
        }
      }
    __syncthreads();
    u16* Dd = s3 ? Kd : Qd;
#pragma unroll
    for (int rt = 0; rt < 8; ++rt) {
      const int m = wave * 32 + rt * 4 + (lane >> 4);
      const int jh = (lane >> 3) & 1, jo = (lane & 7) * 8;
      bf16x8 v = *(const bf16x8*)&Ts[m * 136 + jh * 64 + jo];
      const int jr = j0 + jh * 64 + jo - s3 * 768;
      const int h = jr >> 6, d = jr & 63;  // d == jo
      const int gm = m0 + m;
      const int b = gm >> 10, n = gm & 1023;
      *(bf16x8*)&Dd[((size_t)(b * 12 + h) * 1024 + n) * 64 + d] = v;
    }
  }
}

// ---------------------------------------------------------------- flash attention
// Wave q-tile = 64 rows (block = 256 q rows): same K/V LDS bytes feed 2x the
// MFMA work (LDS pipe is per-CU shared; it was the binding resource at q=32).
// S^T trick: st C-layout == K=16 A-layout, so P=exp2(st) feeds PV directly
// from registers. Q pre-scaled by SCALE*log2e; P=exp2(s), denominators via
// ones-MFMA on the matrix pipe.
__global__ __launch_bounds__(256, 2)
void attn_kernel(const u16* __restrict__ Qx, const u16* __restrict__ Kx, const u16* __restrict__ Vtx,
                 const u16* __restrict__ Qy, const u16* __restrict__ Ky, const u16* __restrict__ Vty,
                 u16* __restrict__ Ox, u16* __restrict__ Oy) {
  __shared__ alignas(16) u16 Ks[2][64 * 64];   // [kv][d], 16B-chunk swizzled
  __shared__ alignas(16) u16 Vs[2][64 * 64];   // [d][kv], 16B-chunk swizzled
  const int br = blockIdx.z;
  const u16* Q = br ? Qy : Qx;
  const u16* K = br ? Ky : Kx;
  const u16* V = br ? Vtx : Vty;  // swapped-V cross attention
  u16* O = br ? Oy : Ox;
  const int bh = blockIdx.y;
  const int q0 = blockIdx.x * 256;
  const int tid = threadIdx.x;
  const int wave = tid >> 6, lane = tid & 63;
  const int quad = lane >> 4, l16 = lane & 15;
  const int l7 = l16 & 7;
  const int r8 = (lane >> 3) & 7;
  const int sw = ((lane & 7) ^ r8) * 8;        // swizzled chunk (u16 offset)

  const u16* Qb = Q + (size_t)bh * 65536;
  const u16* Kb = K + (size_t)bh * 65536;
  const u16* Vb = V + (size_t)bh * 65536;

  // loop-invariant Q fragments: wave owns 64 q rows (mt 0..3)
  bf16x8 qf[4][2];
#pragma unroll
  for (int mt = 0; mt < 4; ++mt)
#pragma unroll
    for (int kc = 0; kc < 2; ++kc)
      qf[mt][kc] = *(const bf16x8*)(Qb + (size_t)(q0 + wave * 64 + mt * 16 + l16) * 64 + kc * 32 + quad * 8);

  f32x4 oacc[4][4] = {};
  f32x4 lsum[4] = {};
  bf16x4 ones4;
#pragma unroll
  for (int j = 0; j < 4; ++j) ones4[j] = (short)0x3f80;  // 1.0bf16

  const int krow = wave * 16 + r8;

#pragma unroll
  for (int c = 0; c < 2; ++c) {
    async16(Kb + (size_t)(krow + c * 8) * 64 + sw, (char*)Ks[0] + wave * 2048 + c * 1024);
    async16(Vb + (size_t)(krow + c * 8) * 1024 + sw, (char*)Vs[0] + wave * 2048 + c * 1024);
  }

  for (int it = 0; it < 16; ++it) {
    const int p = it & 1;
    BAR_FULL;
    if (it < 15) {
      const int kv1 = (it + 1) * 64;
#pragma unroll
      for (int c = 0; c < 2; ++c) {
        async16(Kb + (size_t)(kv1 + krow + c * 8) * 64 + sw, (char*)Ks[p ^ 1] + wave * 2048 + c * 1024);
        async16(Vb + (size_t)(krow + c * 8) * 1024 + kv1 + sw, (char*)Vs[p ^ 1] + wave * 2048 + c * 1024);
      }
    }

    const u16* Kp = Ks[p];
    const u16* Vp = Vs[p];

#pragma unroll
    for (int kt = 0; kt < 4; ++kt) {
      // S^T = K Q^T for this 16-kv slab: lane holds q=l16, kv=kt*16+quad*4+r
      f32x4 st[4] = {};
#pragma unroll
      for (int kc = 0; kc < 2; ++kc) {
        bf16x8 kf = *(const bf16x8*)&Kp[(kt * 16 + l16) * 64 + (((kc * 4 + quad) ^ l7) * 8)];
#pragma unroll
        for (int mt = 0; mt < 4; ++mt)
          st[mt] = MFMA_BF16(kf, qf[mt][kc], st[mt], 0, 0, 0);
      }
      // P = exp2(S^T) packed straight into K=16 A-operand fragments
      bf16x4 pf[4];
#pragma unroll
      for (int mt = 0; mt < 4; ++mt)
        pf[mt] = pack4(EXP2F(st[mt][0]), EXP2F(st[mt][1]),
                       EXP2F(st[mt][2]), EXP2F(st[mt][3]));
      // V B-fragments for this kv slab
      bf16x4 vf[4];
      const int c16 = kt * 2 + (quad >> 1);
      const int hh = (quad & 1) * 4;
#pragma unroll
      for (int dt = 0; dt < 4; ++dt)
        vf[dt] = *(const bf16x4*)&Vp[(dt * 16 + l16) * 64 + ((c16 ^ l7) * 8) + hh];
      // O += P @ V ; lsum += P @ ones
#pragma unroll
      for (int mt = 0; mt < 4; ++mt) {
#pragma unroll
        for (int dt = 0; dt < 4; ++dt)
          oacc[mt][dt] = MFMA16(pf[mt], vf[dt], oacc[mt][dt]);
        lsum[mt] = MFMA16(pf[mt], ones4, lsum[mt]);
      }
    }
  }

  // epilogue: O / l -> bf16 [b, n, h*64+d]
  const int b = bh / 12, h = bh % 12;
#pragma unroll
  for (int mt = 0; mt < 4; ++mt) {
#pragma unroll
    for (int r = 0; r < 4; ++r) {
      const float inv = 1.0f / lsum[mt][r];
      const int qrow = q0 + wave * 64 + mt * 16 + quad * 4 + r;
      const size_t ob = ((size_t)(b * 1024 + qrow)) * 768 + h * 64;
#pragma unroll
      for (int nt = 0; nt < 4; ++nt)
        O[ob + nt * 16 + l16] = f2b(oacc[mt][nt][r] * inv);
    }
  }
}

// ---------------------------------------------------------------- proj GEMM + bias
__global__ __launch_bounds__(256, 2)
void proj_gemm(const u16* __restrict__ Ox, const u16* __restrict__ Oy,
               const u16* __restrict__ Pxw, const u16* __restrict__ Pyw,
               const float* __restrict__ bx, const float* __restrict__ by,
               float* __restrict__ out) {
  __shared__ alignas(16) char smem[65536];
  const int br = blockIdx.z;
  const u16* A = br ? Oy : Ox;
  const u16* W = br ? Pyw : Pxw;
  const float* bias = br ? by : bx;
  float* op = out + (size_t)br * 6291456;
  const int m0 = blockIdx.x * 128;
  const int j0 = blockIdx.y * 128;
  const int tid = threadIdx.x;
  const int wave = tid >> 6, lane = tid & 63;
  const int quad = lane >> 4, l16 = lane & 15;
  const int wm = wave >> 1, wn = wave & 1;
  const int srow = wave * 32 + (lane >> 3);
  const int scol = (((lane & 7) ^ ((lane >> 3) & 7)) * 8);
  const int l7 = l16 & 7;

  auto stage = [&](int k0, int p) {
#pragma unroll
    for (int c = 0; c < 4; ++c) {
      async16(A + (size_t)(m0 + srow + c * 8) * 768 + k0 + scol,
              smem + p * 16384 + wave * 4096 + c * 1024);
      async16(W + (size_t)(j0 + srow + c * 8) * 768 + k0 + scol,
              smem + 32768 + p * 16384 + wave * 4096 + c * 1024);
    }
  };

  f32x4 acc[4][4] = {};
  stage(0, 0);

  for (int kt = 0; kt < 12; ++kt) {
    const int p = kt & 1;
    BAR_FULL;
    if (kt < 11) stage((kt + 1) * 64, p ^ 1);
    const u16* Ap = (const u16*)smem + p * 8192;
    const u16* Bp = (const u16*)smem + 16384 + p * 8192;
#pragma unroll
    for (int kc = 0; kc < 2; ++kc) {
      bf16x8 af[4], bfr[4];
#pragma unroll
      for (int t = 0; t < 4; ++t) {
        af[t]  = *(const bf16x8*)&Ap[(wm * 64 + t * 16 + l16) * 64 + (((kc * 4 + quad) ^ l7) * 8)];
        bfr[t] = *(const bf16x8*)&Bp[(wn * 64 + t * 16 + l16) * 64 + (((kc * 4 + quad) ^ l7) * 8)];
      }
#pragma unroll
      for (int mt = 0; mt < 4; ++mt)
#pragma unroll
        for (int nt = 0; nt < 4; ++nt)
          acc[mt][nt] = MFMA_BF16(af[mt], bfr[nt], acc[mt][nt], 0, 0, 0);
    }
  }

#pragma unroll
  for (int mt = 0; mt < 4; ++mt) {
#pragma unroll
    for (int nt = 0; nt < 4; ++nt) {
      const int j = j0 + wn * 64 + nt * 16 + l16;
      const float bj = bias[j];
#pragma unroll
      for (int r = 0; r < 4; ++r) {
        const int m = m0 + wm * 64 + mt * 16 + quad * 4 + r;
        op[(size_t)m * 768 + j] = acc[mt][nt][r] + bj;
      }
    }
  }
}

// ---------------------------------------------------------------- launch
extern "C" void kernel_launch(void* const* d_in, const int* in_sizes, int n_in,
                              void* d_out, int out_size, void* d_ws, size_t ws_size,
                              hipStream_t stream) {
  (void)in_sizes; (void)n_in; (void)out_size; (void)ws_size;
  const float* x   = (const float*)d_in[0];
  const float* y   = (const float*)d_in[1];
  const float* xqw = (const float*)d_in[2];
  const float* yqw = (const float*)d_in[3];
  const float* xpw = (const float*)d_in[4];
  const float* xpb = (const float*)d_in[5];
  const float* ypw = (const float*)d_in[6];
  const float* ypb = (const float*)d_in[7];
  float* out = (float*)d_out;

  char* p = (char*)d_ws;
  u16* Xb  = (u16*)p; p += 12582912;   // contiguous bf16 block for cvt_all:
  u16* Yb  = (u16*)p; p += 12582912;   // Xb Yb Wxb Wyb Pxb Pyb
  u16* Wxb = (u16*)p; p += 3538944;
  u16* Wyb = (u16*)p; p += 3538944;
  u16* Pxb = (u16*)p; p += 1179648;
  u16* Pyb = (u16*)p; p += 1179648;
  u16* Qx  = (u16*)p; p += 12582912;   // [b,h,n,d] bf16 (pre-scaled by QSCALE)
  u16* Kx  = (u16*)p; p += 12582912;
  u16* Vtx = (u16*)p; p += 12582912;   // [b,h,d,n] bf16
  u16* Qy  = (u16*)p; p += 12582912;
  u16* Ky  = (u16*)p; p += 12582912;
  u16* Vty = (u16*)p; p += 12582912;
  u16* Ox  = Xb;  // alias: Xb/Yb dead after qkv_gemm (stream-ordered)
  u16* Oy  = Yb;

  cvt_all<<<16896, 256, 0, stream>>>(x, y, xqw, yqw, xpw, ypw, Xb);

  qkv_gemm<<<dim3(64, 18, 2), 256, 0, stream>>>(Xb, Yb, Wxb, Wyb,
                                                Qx, Kx, Vtx, Qy, Ky, Vty);
  attn_kernel<<<dim3(4, 96, 2), 256, 0, stream>>>(Qx, Kx, Vtx, Qy, Ky, Vty, Ox, Oy);
  proj_gemm<<<dim3(64, 6, 2), 256, 0, stream>>>(Ox, Oy, Pxb, Pyb, xpb, ypb, out);
}